// Round 16
// baseline (1050.096 us; speedup 1.0000x reference)
//
#include <hip/hip_runtime.h>
#include <stdint.h>

#define B_ROWS 16384
#define NIN    784
#define NH     500
#define NHP    512
#define NOUT   10
#define STEPS  25

// Verified reference semantics (R15 PASS):
//   fc1: per (row,n): f32 FMA chains ascending k, k-blocks [0,512)+[512,784),
//        combined by one __fadd_rn; + b1 via one __fadd_rn.
//   LIF (both layers), per-op f32, no contraction:
//        m = fsub(fadd(fmul(0.95f,m),c),reset);  spike = m > 1.0f
//   fc2: per (row,o,st): single ascending-h chain over h=0..500 of conditional
//        fadd(acc, w2[o][h]) when spike bit set  (== fmaf(bit, w, acc)).
// This round: same math, restructured for throughput.

// ---------------- K1: fc1 + LIF1 -> spike masks (u32 per (row,unit)) ----------------
// 16 rows/block; 256 threads = 128 unit-groups (4 units) x 2 row-halves (8 rows).
// Register micro-tile acc[8][4]: 128 FMAs per 12 vector loads.

__device__ __forceinline__ void k1_seg(
    const float (*xs)[NIN], int r0,
    const float* __restrict__ wp0, const float* __restrict__ wp1,
    const float* __restrict__ wp2, const float* __restrict__ wp3,
    int k0, int k1, float acc[8][4])
{
    for (int k = k0; k < k1; k += 4) {
        float4 wv[4];
        wv[0] = *(const float4*)(wp0 + k);
        wv[1] = *(const float4*)(wp1 + k);
        wv[2] = *(const float4*)(wp2 + k);
        wv[3] = *(const float4*)(wp3 + k);
#pragma unroll
        for (int r = 0; r < 8; ++r) {
            const float4 xv = *(const float4*)&xs[r0 + r][k];
#pragma unroll
            for (int j = 0; j < 4; ++j) {
                // strict ascending-k chain per (row,unit)
                acc[r][j] = fmaf(xv.x, wv[j].x, acc[r][j]);
                acc[r][j] = fmaf(xv.y, wv[j].y, acc[r][j]);
                acc[r][j] = fmaf(xv.z, wv[j].z, acc[r][j]);
                acc[r][j] = fmaf(xv.w, wv[j].w, acc[r][j]);
            }
        }
    }
}

__global__ __launch_bounds__(256) void k1_fc1(
    const float* __restrict__ x, const float* __restrict__ w1,
    const float* __restrict__ b1, uint32_t* __restrict__ masks_g)
{
    __shared__ float xs[16][NIN];            // 50,176 B
    const int t    = threadIdx.x;
    const int row0 = blockIdx.x * 16;

    for (int i = t; i < 16 * (NIN / 4); i += 256) {
        const int r = i / (NIN / 4), q = i - r * (NIN / 4);
        *(float4*)&xs[r][q * 4] = *(const float4*)(x + (size_t)(row0 + r) * NIN + q * 4);
    }
    __syncthreads();

    const int ur = t & 127;                  // unit group (4 units)
    const int rh = t >> 7;                   // row half (8 rows)
    if (ur >= 125) return;                   // 500 = 125*4; no barriers after this
    const int n0 = ur * 4;
    const int r0 = rh * 8;

    const float* wp0 = w1 + (size_t)(n0 + 0) * NIN;
    const float* wp1 = w1 + (size_t)(n0 + 1) * NIN;
    const float* wp2 = w1 + (size_t)(n0 + 2) * NIN;
    const float* wp3 = w1 + (size_t)(n0 + 3) * NIN;

    float accA[8][4], accB[8][4];
#pragma unroll
    for (int r = 0; r < 8; ++r)
#pragma unroll
        for (int j = 0; j < 4; ++j) { accA[r][j] = 0.f; accB[r][j] = 0.f; }

    k1_seg(xs, r0, wp0, wp1, wp2, wp3, 0, 512, accA);    // block 1: [0,512)
    k1_seg(xs, r0, wp0, wp1, wp2, wp3, 512, 784, accB);  // block 2: [512,784)

    float bb[4];
#pragma unroll
    for (int j = 0; j < 4; ++j) bb[j] = b1[n0 + j];

#pragma unroll
    for (int r = 0; r < 8; ++r) {
        uint32_t bits4[4];
#pragma unroll
        for (int j = 0; j < 4; ++j) {
            const float dot = __fadd_rn(accA[r][j], accB[r][j]);  // combine blocks
            const float c   = __fadd_rn(dot, bb[j]);              // + bias
            float m = 0.f;
            uint32_t bits = 0;
#pragma unroll
            for (int st = 0; st < STEPS; ++st) {
                const float rs = (m > 1.0f) ? 1.0f : 0.0f;        // reset from PREV mem
                m = __fsub_rn(__fadd_rn(__fmul_rn(0.95f, m), c), rs);
                bits |= ((m > 1.0f) ? 1u : 0u) << st;
            }
            bits4[j] = bits;
        }
        *(uint4*)&masks_g[(size_t)(row0 + r0 + r) * NHP + n0] =
            make_uint4(bits4[0], bits4[1], bits4[2], bits4[3]);
    }
}

// ---------------- K2: fc2 + LIF2 -> outputs ----------------
// 25 rows/block, 250 active threads: thread = (row, o) owns all 25 step-chains
// and the LIF2 scan. fmaf(bit, w, acc) == reference conditional fadd exactly.

#define K2_RPB 25

__global__ __launch_bounds__(256) void k2_fc2(
    const uint32_t* __restrict__ masks_g, const float* __restrict__ w2,
    const float* __restrict__ b2, float* __restrict__ out)
{
    __shared__ uint32_t ms[K2_RPB][NHP];     // 51,200 B
    __shared__ float    w2s[NH][NOUT];       // 20,000 B
    __shared__ float    b2s[NOUT];

    const int t    = threadIdx.x;
    const int row0 = blockIdx.x * K2_RPB;
    const int rlim = (B_ROWS - row0 < K2_RPB) ? (B_ROWS - row0) : K2_RPB;

    for (int i = t; i < NH * NOUT; i += 256) {
        const int h = i / NOUT, o = i - h * NOUT;
        w2s[h][o] = w2[o * NH + h];
    }
    if (t < NOUT) b2s[t] = b2[t];
    for (int i = t; i < rlim * (NHP / 4); i += 256) {
        const int r = i / (NHP / 4), q = i - r * (NHP / 4);
        *(uint4*)&ms[r][q * 4] = *(const uint4*)(masks_g + (size_t)(row0 + r) * NHP + q * 4);
    }
    __syncthreads();

    const int r = t / NOUT;
    const int o = t - r * NOUT;
    if (t >= K2_RPB * NOUT || r >= rlim) return;   // no barriers after this

    float a[STEPS];
#pragma unroll
    for (int st = 0; st < STEPS; ++st) a[st] = 0.f;

    for (int h = 0; h < NH; ++h) {
        const uint32_t mw = ms[r][h];
        const float wv = w2s[h][o];
#pragma unroll
        for (int st = 0; st < STEPS; ++st) {
            const float s = (float)((mw >> st) & 1u);
            a[st] = fmaf(s, wv, a[st]);              // ascending-h chain, exact
        }
    }

    float* spk_out = out;
    float* mem_out = out + (size_t)STEPS * B_ROWS * NOUT;
    const size_t base = (size_t)(row0 + r) * NOUT + o;
    const float bo = b2s[o];
    float m = 0.f;
#pragma unroll
    for (int st = 0; st < STEPS; ++st) {
        const float c  = __fadd_rn(a[st], bo);       // gemm chain + bias
        const float rs = (m > 1.0f) ? 1.0f : 0.0f;   // reset from PREVIOUS mem
        m = __fsub_rn(__fadd_rn(__fmul_rn(0.95f, m), c), rs);
        const size_t idx = (size_t)st * (B_ROWS * NOUT) + base;
        spk_out[idx] = (m > 1.0f) ? 1.0f : 0.0f;
        mem_out[idx] = m;
    }
}

extern "C" void kernel_launch(void* const* d_in, const int* in_sizes, int n_in,
                              void* d_out, int out_size, void* d_ws, size_t ws_size,
                              hipStream_t stream)
{
    const float* x  = (const float*)d_in[0];
    const float* w1 = (const float*)d_in[1];
    const float* b1 = (const float*)d_in[2];
    const float* w2 = (const float*)d_in[3];
    const float* b2 = (const float*)d_in[4];
    float* out = (float*)d_out;

    uint32_t* masks_g = (uint32_t*)d_ws;     // 16384*512*4 = 33,554,432 B

    k1_fc1<<<dim3(B_ROWS / 16), 256, 0, stream>>>(x, w1, b1, masks_g);
    k2_fc2<<<dim3((B_ROWS + K2_RPB - 1) / K2_RPB), 256, 0, stream>>>(masks_g, w2, b2, out);
}

// Round 17
// 889.541 us; speedup vs baseline: 1.1805x; 1.1805x over previous
//
#include <hip/hip_runtime.h>
#include <stdint.h>

#define B_ROWS 16384
#define NIN    784
#define NH     500
#define NHP    512
#define NOUT   10
#define STEPS  25

// Verified reference semantics (R15 PASS):
//   fc1: per (row,n): f32 fmaf chains ascending k, k-blocks [0,512)+[512,784),
//        combined by one __fadd_rn; + b1 via one __fadd_rn.
//   LIF (both layers), per-op f32: m = fsub(fadd(fmul(0.95f,m),c),reset); spike = m>1
//   fc2: ascending-h conditional fadd chain (== fmaf(bit,w,acc)), + b2, LIF2.

// ---------------- K1: fc1 + LIF1 -> masks ----------------
// Block: 256 thr = 4 waves; wave w handles rows row0+4w..+3; lane handles units
// {lane+64j, j=0..7}. w1 staged per 16-k chunk in LDS (coalesced global reads,
// XOR-swizzled quads for bank spread); x reads wave-uniform (broadcast).
// acc[8][4] dual-bank (A: k<512, B: k>=512) preserves the exact BLIS split.

#define KT    16
#define NCH   49      // 784/16
#define CHSPL 32      // chunks 0..31 -> k<512

template <int NCHUNKS>
__device__ __forceinline__ void k1_span(
    const float* __restrict__ x, const float* __restrict__ w1,
    float* __restrict__ wt, int t, int lane, int row0, int ch0,
    float acc[8][4])
{
    for (int c = 0; c < NCHUNKS; ++c) {
        const int k0 = (ch0 + c) * KT;
        __syncthreads();                    // prior compute done before restage
        // stage 512 units x 16 k (2048 float4 by 256 threads)
#pragma unroll
        for (int s = 0; s < 8; ++s) {
            const int i = t + 256 * s;
            const int u = i >> 2, q = i & 3;
            float4 v = make_float4(0.f, 0.f, 0.f, 0.f);
            if (u < NH) v = *(const float4*)(w1 + (size_t)u * NIN + k0 + q * 4);
            const int qs = q ^ ((u >> 2) & 3);          // bank-spread swizzle
            *(float4*)&wt[u * 16 + qs * 4] = v;
        }
        __syncthreads();
#pragma unroll
        for (int q = 0; q < 4; ++q) {
            float4 xq[4];
#pragma unroll
            for (int r = 0; r < 4; ++r)                  // wave-uniform loads
                xq[r] = *(const float4*)(x + (size_t)(row0 + r) * NIN + k0 + q * 4);
            const int qs = q ^ ((lane >> 2) & 3);
#pragma unroll
            for (int j = 0; j < 8; ++j) {
                const float4 wv = *(const float4*)&wt[(64 * j + lane) * 16 + qs * 4];
#pragma unroll
                for (int r = 0; r < 4; ++r) {            // ascending k per chain
                    acc[j][r] = fmaf(xq[r].x, wv.x, acc[j][r]);
                    acc[j][r] = fmaf(xq[r].y, wv.y, acc[j][r]);
                    acc[j][r] = fmaf(xq[r].z, wv.z, acc[j][r]);
                    acc[j][r] = fmaf(xq[r].w, wv.w, acc[j][r]);
                }
            }
        }
    }
}

__global__ __launch_bounds__(256) void k1_fc1(
    const float* __restrict__ x, const float* __restrict__ w1,
    const float* __restrict__ b1, uint32_t* __restrict__ masks_g)
{
    __shared__ float wt[NHP * KT];          // 32,768 B
    const int t    = threadIdx.x;
    const int lane = t & 63;
    const int rg   = t >> 6;                // wave id 0..3
    const int row0 = blockIdx.x * 16 + rg * 4;

    float accA[8][4], accB[8][4];
#pragma unroll
    for (int j = 0; j < 8; ++j)
#pragma unroll
        for (int r = 0; r < 4; ++r) { accA[j][r] = 0.f; accB[j][r] = 0.f; }

    k1_span<CHSPL>(x, w1, wt, t, lane, row0, 0, accA);         // k in [0,512)
    k1_span<NCH - CHSPL>(x, w1, wt, t, lane, row0, CHSPL, accB); // [512,784)

#pragma unroll
    for (int j = 0; j < 8; ++j) {
        const int u = 64 * j + lane;
        if (u >= NH) continue;
        const float bb = b1[u];
#pragma unroll
        for (int r = 0; r < 4; ++r) {
            const float dot = __fadd_rn(accA[j][r], accB[j][r]);  // combine blocks
            const float c   = __fadd_rn(dot, bb);                 // + bias
            float m = 0.f;
            uint32_t bits = 0;
#pragma unroll
            for (int st = 0; st < STEPS; ++st) {
                const float rs = (m > 1.0f) ? 1.0f : 0.0f;        // reset from PREV mem
                m = __fsub_rn(__fadd_rn(__fmul_rn(0.95f, m), c), rs);
                bits |= ((m > 1.0f) ? 1u : 0u) << st;
            }
            masks_g[(size_t)(row0 + r) * NHP + u] = bits;         // coalesced b32
        }
    }
}

// ---------------- K2: fc2 + LIF2 -> outputs (R16 structure, passing) ----------------
#define K2_RPB 25

__global__ __launch_bounds__(256) void k2_fc2(
    const uint32_t* __restrict__ masks_g, const float* __restrict__ w2,
    const float* __restrict__ b2, float* __restrict__ out)
{
    __shared__ uint32_t ms[K2_RPB][NHP];     // 51,200 B
    __shared__ float    w2s[NH][NOUT];       // 20,000 B
    __shared__ float    b2s[NOUT];

    const int t    = threadIdx.x;
    const int row0 = blockIdx.x * K2_RPB;
    const int rlim = (B_ROWS - row0 < K2_RPB) ? (B_ROWS - row0) : K2_RPB;

    for (int i = t; i < NH * NOUT; i += 256) {
        const int h = i / NOUT, o = i - h * NOUT;
        w2s[h][o] = w2[o * NH + h];
    }
    if (t < NOUT) b2s[t] = b2[t];
    for (int i = t; i < rlim * (NHP / 4); i += 256) {
        const int r = i / (NHP / 4), q = i - r * (NHP / 4);
        *(uint4*)&ms[r][q * 4] = *(const uint4*)(masks_g + (size_t)(row0 + r) * NHP + q * 4);
    }
    __syncthreads();

    const int r = t / NOUT;
    const int o = t - r * NOUT;
    if (t >= K2_RPB * NOUT || r >= rlim) return;

    float a[STEPS];
#pragma unroll
    for (int st = 0; st < STEPS; ++st) a[st] = 0.f;

    for (int h = 0; h < NH; ++h) {
        const uint32_t mw = ms[r][h];
        const float wv = w2s[h][o];
#pragma unroll
        for (int st = 0; st < STEPS; ++st) {
            const float s = (float)((mw >> st) & 1u);
            a[st] = fmaf(s, wv, a[st]);              // ascending-h chain, exact
        }
    }

    float* spk_out = out;
    float* mem_out = out + (size_t)STEPS * B_ROWS * NOUT;
    const size_t base = (size_t)(row0 + r) * NOUT + o;
    const float bo = b2s[o];
    float m = 0.f;
#pragma unroll
    for (int st = 0; st < STEPS; ++st) {
        const float c  = __fadd_rn(a[st], bo);
        const float rs = (m > 1.0f) ? 1.0f : 0.0f;
        m = __fsub_rn(__fadd_rn(__fmul_rn(0.95f, m), c), rs);
        const size_t idx = (size_t)st * (B_ROWS * NOUT) + base;
        spk_out[idx] = (m > 1.0f) ? 1.0f : 0.0f;
        mem_out[idx] = m;
    }
}

extern "C" void kernel_launch(void* const* d_in, const int* in_sizes, int n_in,
                              void* d_out, int out_size, void* d_ws, size_t ws_size,
                              hipStream_t stream)
{
    const float* x  = (const float*)d_in[0];
    const float* w1 = (const float*)d_in[1];
    const float* b1 = (const float*)d_in[2];
    const float* w2 = (const float*)d_in[3];
    const float* b2 = (const float*)d_in[4];
    float* out = (float*)d_out;

    uint32_t* masks_g = (uint32_t*)d_ws;     // 33,554,432 B

    k1_fc1<<<dim3(B_ROWS / 16), 256, 0, stream>>>(x, w1, b1, masks_g);
    k2_fc2<<<dim3((B_ROWS + K2_RPB - 1) / K2_RPB), 256, 0, stream>>>(masks_g, w2, b2, out);
}